// Round 2
// 401.432 us; speedup vs baseline: 1.0371x; 1.0371x over previous
//
#include <hip/hip_runtime.h>

#define N_NODES 100000
#define N_EDGES 3200000
#define C_IN 256
#define C_H 64
#define C_OUT 128
#define NB 391       // ceil(N_NODES/256) buckets of 256 nodes
#define G2F 625      // blocks for fused gemm2+pool
#define NTILES 6250  // N_NODES/16
#define NT16 6250    // gather tiles of 16 nodes
#define G_GM 1563    // ceil(NT16/4)
#define CH1 8192     // edges per block in hist/scatter1

typedef unsigned int u32;
typedef unsigned short u16;
typedef unsigned long long u64;
typedef __attribute__((ext_vector_type(8))) short bf16x8;
typedef __attribute__((ext_vector_type(4))) float f32x4;

typedef __attribute__((address_space(3))) unsigned int l_u32;
typedef __attribute__((address_space(1))) const unsigned int g_u32;

// ---------- bf16 helpers ----------
__device__ __forceinline__ float bflo(u32 p) {
    union { u32 i; float f; } v; v.i = p << 16; return v.f;
}
__device__ __forceinline__ float bfhi(u32 p) {
    union { u32 i; float f; } v; v.i = p & 0xffff0000u; return v.f;
}
__device__ __forceinline__ float bf2f(u16 u) {
    union { u32 i; float f; } v; v.i = ((u32)u) << 16; return v.f;
}
__device__ __forceinline__ u16 f2bf(float f) {
    union { float f; u32 i; } v; v.f = f;
    u32 x = v.i;
    return (u16)((x + 0x7fffu + ((x >> 16) & 1u)) >> 16);  // RNE
}

__device__ __forceinline__ void gll16(const void* gp, const u16* lp) {
    __builtin_amdgcn_global_load_lds((g_u32*)gp, (l_u32*)lp, 16, 0, 0);
}

// ---------- slim detection: flags + small tensors ----------
__global__ void k_detect(const void* __restrict__ x, const void* __restrict__ ei,
                         const void* __restrict__ b1, const void* __restrict__ b2,
                         const void* __restrict__ fcW, const void* __restrict__ fcb,
                         int* __restrict__ flags,
                         float* __restrict__ b1c, float* __restrict__ b2c,
                         float* __restrict__ fcWc, float* __restrict__ fcbc) {
    __shared__ int sf[2];
    int t = threadIdx.x;
    if (t < 64) {
        u32 w = ((const u32*)x)[t];
        u32 low = w & 0xffffu;
        int e = (int)((low >> 7) & 0xff);
        bool inw = (e > 96 && e < 160) || (low == 0);
        u64 m = __ballot(inw);
        if (t == 0) sf[0] = (__popcll(m) >= 60) ? 1 : 0;
    } else if (t < 128) {
        int i = t - 64;
        u32 w = ((const u32*)ei)[2 * i + 1];
        u64 m = __ballot(w == 0);
        if (i == 0) sf[1] = (m == ~0ull) ? 1 : 0;
    }
    __syncthreads();
    if (t == 0) { flags[0] = sf[0]; flags[1] = sf[1]; }
    int isbf = sf[0];
    if (isbf) {
        const u16* p1 = (const u16*)b1;  const u16* p2 = (const u16*)b2;
        const u16* pw = (const u16*)fcW; const u16* pb = (const u16*)fcb;
        for (int i = t; i < C_H; i += 256) b1c[i] = bf2f(p1[i]);
        for (int i = t; i < C_OUT; i += 256) b2c[i] = bf2f(p2[i]);
        for (int i = t; i < 2 * C_OUT; i += 256) fcWc[i] = bf2f(pw[i]);
        for (int i = t; i < 2; i += 256) fcbc[i] = bf2f(pb[i]);
    } else {
        const float* p1 = (const float*)b1;  const float* p2 = (const float*)b2;
        const float* pw = (const float*)fcW; const float* pb = (const float*)fcb;
        for (int i = t; i < C_H; i += 256) b1c[i] = p1[i];
        for (int i = t; i < C_OUT; i += 256) b2c[i] = p2[i];
        for (int i = t; i < 2 * C_OUT; i += 256) fcWc[i] = pw[i];
        for (int i = t; i < 2; i += 256) fcbc[i] = pb[i];
    }
}

// ---------- parallel prep: W1m/W2m frag-order swizzles + bucket_cnt zero ----------
__global__ __launch_bounds__(256) void k_prep(const void* __restrict__ W1,
                                              const void* __restrict__ W2,
                                              const int* __restrict__ flags,
                                              u16* __restrict__ W1m, u16* __restrict__ W2m,
                                              u32* __restrict__ bucket_cnt) {
    int b = blockIdx.x, t = threadIdx.x;
    int isbf = flags[0];
    int i = b * 256 + t;
    if (i < NB) bucket_cnt[i] = 0;
    if (i < C_IN * C_H) {
        const u16* w1b = (const u16*)W1; const float* w1f = (const float*)W1;
        int j = i & 7, lane = (i >> 3) & 63, nt = (i >> 9) & 3, k0 = i >> 11;
        int k = k0 * 32 + ((lane >> 4) & 3) * 8 + j;
        int n = nt * 16 + (lane & 15);
        W1m[i] = isbf ? w1b[k * C_H + n] : f2bf(w1f[k * C_H + n]);
    } else {
        int i2 = i - C_IN * C_H;
        const u16* w2b = (const u16*)W2; const float* w2f = (const float*)W2;
        int j = i2 & 7, lane = (i2 >> 3) & 63, nt = (i2 >> 9) & 7, k0 = (i2 >> 12) & 1;
        int k = k0 * 32 + ((lane >> 4) & 3) * 8 + j;
        int n = nt * 16 + (lane & 15);
        W2m[i2] = isbf ? w2b[k * C_OUT + n] : f2bf(w2f[k * C_OUT + n]);
    }
}

// ---------- bucket histogram over dst>>8 ----------
__global__ __launch_bounds__(256) void k_hist1(const int* __restrict__ ei,
                                               const int* __restrict__ flags,
                                               u32* __restrict__ bucket_cnt) {
    __shared__ u32 h[NB];
    int t = threadIdx.x;
    int is64 = flags[1];
    for (int i = t; i < NB; i += 256) h[i] = 0;
    __syncthreads();
    int e0 = blockIdx.x * CH1;
    int nv = min(CH1, N_EDGES - e0);
    for (int i = t; i < nv; i += 256) {
        int e = e0 + i;
        int d = is64 ? ei[2 * (N_EDGES + e)] : ei[N_EDGES + e];
        atomicAdd(&h[d >> 8], 1u);
    }
    __syncthreads();
    for (int i = t; i < NB; i += 256)
        if (h[i]) atomicAdd(&bucket_cnt[i], h[i]);
}

// ---------- scan bucket counts -> base + cursor ----------
__global__ __launch_bounds__(512) void k_bscan(const u32* __restrict__ bucket_cnt,
                                               u32* __restrict__ bucket_base,
                                               u32* __restrict__ bucket_cursor,
                                               int* __restrict__ rowptr) {
    __shared__ u32 sm[512];
    int t = threadIdx.x;
    u32 v = (t < NB) ? bucket_cnt[t] : 0;
    sm[t] = v;
    __syncthreads();
    for (int off = 1; off < 512; off <<= 1) {
        u32 a = (t >= off) ? sm[t - off] : 0;
        __syncthreads();
        sm[t] += a;
        __syncthreads();
    }
    if (t < NB) {
        u32 excl = sm[t] - v;
        bucket_base[t] = excl;
        bucket_cursor[t] = excl;
    }
    if (t == 0) bucket_base[NB] = N_EDGES;
    (void)rowptr;
}

// ---------- pass 1: bucket-sorted staged scatter (line-dense writes) ----------
__global__ __launch_bounds__(512) void k_scatter1(const int* __restrict__ ei,
                                                  const int* __restrict__ flags,
                                                  u32* __restrict__ bucket_cursor,
                                                  u32* __restrict__ ebuf) {
    __shared__ u32 cnt[NB];
    __shared__ u32 lcur[NB];
    __shared__ u32 gbase[NB];
    __shared__ u32 lofs[512];
    __shared__ u32 stp[CH1];
    __shared__ u16 stb[CH1];
    int t = threadIdx.x;
    int is64 = flags[1];
    int e0 = blockIdx.x * CH1;
    int nv = min(CH1, N_EDGES - e0);
    for (int i = t; i < NB; i += 512) { cnt[i] = 0; lcur[i] = 0; }
    __syncthreads();
    for (int i = t; i < nv; i += 512) {
        int e = e0 + i;
        int d = is64 ? ei[2 * (N_EDGES + e)] : ei[N_EDGES + e];
        atomicAdd(&cnt[d >> 8], 1u);
    }
    __syncthreads();
    u32 v = (t < NB) ? cnt[t] : 0;
    lofs[t] = v;
    __syncthreads();
    for (int off = 1; off < 512; off <<= 1) {
        u32 a = (t >= off) ? lofs[t - off] : 0;
        __syncthreads();
        lofs[t] += a;
        __syncthreads();
    }
    u32 excl = lofs[t] - v;
    __syncthreads();
    lofs[t] = excl;
    __syncthreads();
    for (int i = t; i < nv; i += 512) {
        int e = e0 + i;
        int d, s;
        if (is64) { d = ei[2 * (N_EDGES + e)]; s = ei[2 * e]; }
        else      { d = ei[N_EDGES + e];       s = ei[e]; }
        int b = d >> 8;
        u32 slot = lofs[b] + atomicAdd(&lcur[b], 1u);
        stp[slot] = ((u32)(d & 255) << 20) | (u32)s;
        stb[slot] = (u16)b;
    }
    __syncthreads();
    for (int b = t; b < NB; b += 512) {
        u32 c = cnt[b];
        gbase[b] = c ? atomicAdd(&bucket_cursor[b], c) : 0;
    }
    __syncthreads();
    for (int s = t; s < nv; s += 512) {
        int b = stb[s];
        ebuf[gbase[b] + (s - lofs[b])] = stp[s];
    }
}

// ---------- pass 2: per-bucket local sort -> csr (byte offsets, WITH self-loops) ----------
// csr row for node n: [rowptr[n], rowptr[n+1]) ; first entry = self (n*128),
// then the in-edges' src byte offsets (src*128). rowptr[N] set by last node.
__global__ __launch_bounds__(256) void k_scatter2(const u32* __restrict__ bucket_base,
                                                  const u32* __restrict__ ebuf,
                                                  int* __restrict__ rowptr,
                                                  float* __restrict__ dinv,
                                                  int* __restrict__ csr) {
    __shared__ int cnt[256];
    __shared__ int pfx[256];
    __shared__ int lcur[256];
    int b = blockIdx.x, t = threadIdx.x;
    int ebeg = (int)bucket_base[b], eend = (int)bucket_base[b + 1];
    int sbeg = ebeg + (b << 8);   // +1 self slot per node in prior (full) buckets
    cnt[t] = 0;
    lcur[t] = 0;
    __syncthreads();
    for (int i = ebeg + t; i < eend; i += 256)
        atomicAdd(&cnt[(ebuf[i] >> 20) & 255], 1);
    __syncthreads();
    int v = cnt[t];
    pfx[t] = v;
    __syncthreads();
    for (int off = 1; off < 256; off <<= 1) {
        int a = (t >= off) ? pfx[t - off] : 0;
        __syncthreads();
        pfx[t] += a;
        __syncthreads();
    }
    int node = (b << 8) + t;
    int rstart = sbeg + (pfx[t] - v) + t;
    if (node < N_NODES) {
        rowptr[node] = rstart;
        dinv[node] = rsqrtf((float)(v + 1));
        csr[rstart] = node << 7;            // self-loop, byte offset
        if (node == N_NODES - 1) {
            rowptr[N_NODES] = rstart + v + 1;
            for (int i = 0; i < 64; ++i) csr[rstart + v + 1 + i] = 0;  // chunk-overrun pad
        }
    }
    __syncthreads();
    for (int i = ebeg + t; i < eend; i += 256) {
        u32 p = ebuf[i];
        int dl = (p >> 20) & 255;
        int pos = sbeg + (pfx[dl] - cnt[dl]) + dl + 1 + atomicAdd(&lcur[dl], 1);
        csr[pos] = (int)((p & 0x1FFFFu) << 7);   // src byte offset
    }
}

// ---------- MFMA GEMM1: g1[N,64] = dinv ⊙ (x[N,256] @ W1[256,64]) ----------
__global__ __launch_bounds__(256) void k_gemm1(const void* __restrict__ xv,
                                               const u16* __restrict__ W1m,
                                               const float* __restrict__ dinv,
                                               u16* __restrict__ g1,
                                               const int* __restrict__ flags) {
    __shared__ u16 wlds[C_IN * C_H];   // 32 KB
    int t = threadIdx.x;
    int isbf = flags[0];
    {
        const uint4* src = (const uint4*)W1m;
        uint4* dst = (uint4*)wlds;
#pragma unroll
        for (int it = 0; it < 8; ++it) dst[t + it * 256] = src[t + it * 256];
    }
    __syncthreads();
    int w = t >> 6, lane = t & 63;
    int quad = lane >> 4, mrow = lane & 15;
    int m0 = blockIdx.x * 128 + w * 32;
    if (m0 >= N_NODES) return;

    bf16x8 a[2][8];
    if (isbf) {
        const u16* xb = (const u16*)xv;
#pragma unroll
        for (int mt = 0; mt < 2; ++mt)
#pragma unroll
            for (int k0 = 0; k0 < 8; ++k0)
                a[mt][k0] = *(const bf16x8*)(xb + (size_t)(m0 + mt * 16 + mrow) * C_IN + k0 * 32 + quad * 8);
    } else {
        const float* xf = (const float*)xv;
#pragma unroll
        for (int mt = 0; mt < 2; ++mt)
#pragma unroll
            for (int k0 = 0; k0 < 8; ++k0) {
                const float* p = xf + (size_t)(m0 + mt * 16 + mrow) * C_IN + k0 * 32 + quad * 8;
                float4 v0 = *(const float4*)p;
                float4 v1 = *(const float4*)(p + 4);
                bf16x8 r;
                r[0] = (short)f2bf(v0.x); r[1] = (short)f2bf(v0.y);
                r[2] = (short)f2bf(v0.z); r[3] = (short)f2bf(v0.w);
                r[4] = (short)f2bf(v1.x); r[5] = (short)f2bf(v1.y);
                r[6] = (short)f2bf(v1.z); r[7] = (short)f2bf(v1.w);
                a[mt][k0] = r;
            }
    }

    float dv0[4], dv1[4];
#pragma unroll
    for (int r = 0; r < 4; ++r) {
        dv0[r] = dinv[m0 + quad * 4 + r];
        dv1[r] = dinv[m0 + 16 + quad * 4 + r];
    }

#pragma unroll
    for (int nt = 0; nt < 4; ++nt) {
        bf16x8 b[8];
#pragma unroll
        for (int k0 = 0; k0 < 8; ++k0)
            b[k0] = *(const bf16x8*)&wlds[((k0 * 4 + nt) * 64 + lane) * 8];
        f32x4 acc0 = {0.f, 0.f, 0.f, 0.f};
        f32x4 acc1 = {0.f, 0.f, 0.f, 0.f};
#pragma unroll
        for (int k0 = 0; k0 < 8; ++k0) {
            acc0 = __builtin_amdgcn_mfma_f32_16x16x32_bf16(a[0][k0], b[k0], acc0, 0, 0, 0);
            acc1 = __builtin_amdgcn_mfma_f32_16x16x32_bf16(a[1][k0], b[k0], acc1, 0, 0, 0);
        }
        int ch = nt * 16 + mrow;   // D: col = lane&15
#pragma unroll
        for (int r = 0; r < 4; ++r) {   // D: row = quad*4 + r
            g1[(size_t)(m0 + quad * 4 + r) * C_H + ch] = f2bf(acc0[r] * dv0[r]);
            g1[(size_t)(m0 + 16 + quad * 4 + r) * C_H + ch] = f2bf(acc1[r] * dv1[r]);
        }
    }
}

// ---------- MFMA gather: out[16-node tile] = Sel(32 edges) x G(32 rows), chunked ----------
// One wave per 16-node tile. CSR (dst-sorted, self-loops included) streamed in
// 32-edge chunks. Staging (call it, lane l): edge E = it*8+(l>>3), channel octet
// l&7 -> LDS byte (E>>3)*1024 + (E&7)*128 + (ch>>3)*16 + (ch&7)*2. Fragments
// assembled with plain ds_read_u16 (deterministic; no tr-read semantics risk).
// A = 0/1 run selector from an 81-entry LUT.
// MODE 0: out = bf16(dinv * relu(dinv*sum + bias))   MODE 1: out = bf16(dinv*sum)
template <int MODE>
__global__ __launch_bounds__(256) void k_gatherM(const int* __restrict__ rowptr,
                                                 const int* __restrict__ csrb,
                                                 const float* __restrict__ dinv,
                                                 const u16* __restrict__ gt,
                                                 const float* __restrict__ bias,
                                                 u16* __restrict__ out) {
    __shared__ __align__(16) u16 hs[4][4096];   // per wave: 2 buffers x 4KB
    __shared__ bf16x8 lut[81];                  // run patterns ones[s..e)
    int t = threadIdx.x;
    if (t < 81) {
        int s = t / 9, e = t - s * 9;
        bf16x8 le;
#pragma unroll
        for (int j = 0; j < 8; ++j) le[j] = (short)((j >= s && j < e) ? 0x3F80 : 0);
        lut[t] = le;
    }
    __syncthreads();
    int w = t >> 6, lane = t & 63;
    int tile = blockIdx.x * 4 + w;
    if (tile >= NT16) return;

    int g16 = lane >> 4, c = lane & 15;
    int n0 = tile << 4;
    int lo = rowptr[n0 + c];
    int hi = rowptr[n0 + c + 1];
    int beg = __shfl(lo, 0, 64);
    int end = __shfl(hi, 15, 64);
    int eidx = lane >> 3;            // edge-in-slice staged by this lane
    int boff = (lane & 7) * 16;      // byte offset (channel octet) within row
    const char* gb = (const char*)gt;
    f32x4 acc0 = {0.f, 0.f, 0.f, 0.f}, acc1 = acc0, acc2 = acc0, acc3 = acc0;
    int nch = (end - beg + 31) >> 5;
    int cb = beg;
    {   // prologue: stage chunk 0 into buffer 0
        u32 o0 = (u32)csrb[cb + eidx];
        u32 o1 = (u32)csrb[cb + 8 + eidx];
        u32 o2 = (u32)csrb[cb + 16 + eidx];
        u32 o3 = (u32)csrb[cb + 24 + eidx];
        gll16(gb + o0 + boff, &hs[w][0]);
        gll16(gb + o1 + boff, &hs[w][512]);
        gll16(gb + o2 + boff, &hs[w][1024]);
        gll16(gb + o3 + boff, &hs[w][1536]);
        asm volatile("" ::: "memory");   // pin: later loads can't hoist above glls
    }
    for (int ci = 0; ci < nch; ++ci) {
        int cbn = cb + 32;
        bool more = (ci + 1 < nch);
        u32 n0o = 0, n1o = 0, n2o = 0, n3o = 0;
        if (more) {                                   // issue next chunk's csr loads
            n0o = (u32)csrb[cbn + eidx];
            n1o = (u32)csrb[cbn + 8 + eidx];
            n2o = (u32)csrb[cbn + 16 + eidx];
            n3o = (u32)csrb[cbn + 24 + eidx];
        }
        if (more) asm volatile("s_waitcnt vmcnt(4)" ::: "memory");   // staging glls done
        else      asm volatile("s_waitcnt vmcnt(0)" ::: "memory");
        // fragment assembly: lane (c,g16), element (j,cht) at
        // buf + g16*1024 + j*128 + cht*32 + (c>>3)*16 + (c&7)*2   [bytes]
        const u16* lp = &hs[w][((ci & 1) << 11) + g16 * 512 + ((c >> 3) << 3) + (c & 7)];
        bf16x8 bfr[4];
#pragma unroll
        for (int cht = 0; cht < 4; ++cht) {
            u32 w0 = (u32)lp[0 * 64 + cht * 16] | ((u32)lp[1 * 64 + cht * 16] << 16);
            u32 w1 = (u32)lp[2 * 64 + cht * 16] | ((u32)lp[3 * 64 + cht * 16] << 16);
            u32 w2 = (u32)lp[4 * 64 + cht * 16] | ((u32)lp[5 * 64 + cht * 16] << 16);
            u32 w3 = (u32)lp[6 * 64 + cht * 16] | ((u32)lp[7 * 64 + cht * 16] << 16);
            union { u32 u[4]; bf16x8 v; } z;
            z.u[0] = w0; z.u[1] = w1; z.u[2] = w2; z.u[3] = w3;
            bfr[cht] = z.v;
        }
        int cbg = cb + g16 * 8;
        int s0 = min(max(lo - cbg, 0), 8);
        int e0 = min(max(hi - cbg, 0), 8);
        bf16x8 af = lut[s0 * 9 + e0];
        acc0 = __builtin_amdgcn_mfma_f32_16x16x32_bf16(af, bfr[0], acc0, 0, 0, 0);
        acc1 = __builtin_amdgcn_mfma_f32_16x16x32_bf16(af, bfr[1], acc1, 0, 0, 0);
        acc2 = __builtin_amdgcn_mfma_f32_16x16x32_bf16(af, bfr[2], acc2, 0, 0, 0);
        acc3 = __builtin_amdgcn_mfma_f32_16x16x32_bf16(af, bfr[3], acc3, 0, 0, 0);
        if (more) {                                   // stage next chunk, other buffer
            int bo = ((ci + 1) & 1) << 11;
            gll16(gb + n0o + boff, &hs[w][bo]);
            gll16(gb + n1o + boff, &hs[w][bo + 512]);
            gll16(gb + n2o + boff, &hs[w][bo + 1024]);
            gll16(gb + n3o + boff, &hs[w][bo + 1536]);
            asm volatile("" ::: "memory");   // pin: next iter's csr loads stay below
        }
        cb = cbn;
    }
    // epilogue: D row = node (lane>>4)*4+r, D col = channel cht*16 + (lane&15)
    float dv[4];
    int nb = n0 + g16 * 4;
#pragma unroll
    for (int r = 0; r < 4; ++r) dv[r] = dinv[nb + r];
    u16* ob = out + (size_t)nb * C_H + c;
#define EPI(ACC, CHT)                                                              \
    {                                                                              \
        float bs = (MODE == 0) ? bias[CHT * 16 + c] : 0.f;                         \
        _Pragma("unroll")                                                          \
        for (int r = 0; r < 4; ++r) {                                              \
            float val = (MODE == 0) ? dv[r] * fmaxf(dv[r] * ACC[r] + bs, 0.f)      \
                                    : dv[r] * ACC[r];                              \
            ob[r * C_H + CHT * 16] = f2bf(val);                                    \
        }                                                                          \
    }
    EPI(acc0, 0) EPI(acc1, 1) EPI(acc2, 2) EPI(acc3, 3)
#undef EPI
}

// ---------- fused MFMA GEMM2 + bias + relu + mean-pool partials ----------
__global__ __launch_bounds__(256) void k_fused2(const u16* __restrict__ aggb,
                                                const u16* __restrict__ W2m,
                                                const float* __restrict__ b2c,
                                                float* __restrict__ partial) {
    __shared__ float psum[4 * 8 * 64];   // [wave][nt][lane], 8 KB
    int t = threadIdx.x;
    int w = t >> 6, lane = t & 63;
    int quad = lane >> 4, m = lane & 15;

    bf16x8 b[2][8];
#pragma unroll
    for (int k0 = 0; k0 < 2; ++k0)
#pragma unroll
        for (int nt = 0; nt < 8; ++nt)
            b[k0][nt] = *(const bf16x8*)&W2m[((k0 * 8 + nt) * 64 + lane) * 8];

    float pacc[8] = {0.f, 0.f, 0.f, 0.f, 0.f, 0.f, 0.f, 0.f};
    float bias[8];
#pragma unroll
    for (int nt = 0; nt < 8; ++nt) bias[nt] = b2c[nt * 16 + m];

    for (int tile = blockIdx.x * 4 + w; tile < NTILES; tile += G2F * 4) {
        const u16* arow = aggb + (size_t)(tile * 16 + m) * C_H + quad * 8;
        bf16x8 a0 = *(const bf16x8*)(arow);
        bf16x8 a1 = *(const bf16x8*)(arow + 32);
#pragma unroll
        for (int nt = 0; nt < 8; ++nt) {
            f32x4 acc = {0.f, 0.f, 0.f, 0.f};
            acc = __builtin_amdgcn_mfma_f32_16x16x32_bf16(a0, b[0][nt], acc, 0, 0, 0);
            acc = __builtin_amdgcn_mfma_f32_16x16x32_bf16(a1, b[1][nt], acc, 0, 0, 0);
#pragma unroll
            for (int r = 0; r < 4; ++r)
                pacc[nt] += fmaxf(acc[r] + bias[nt], 0.f);
        }
    }
#pragma unroll
    for (int nt = 0; nt < 8; ++nt) psum[(w * 8 + nt) * 64 + lane] = pacc[nt];
    __syncthreads();
    if (t < 128) {
        int nt = t >> 4, m2 = t & 15;
        float s = 0.f;
#pragma unroll
        for (int ww = 0; ww < 4; ++ww)
#pragma unroll
            for (int q = 0; q < 4; ++q)
                s += psum[(ww * 8 + nt) * 64 + q * 16 + m2];
        partial[blockIdx.x * C_OUT + t] = s;   // ch = nt*16 + m2 = t
    }
}

// ---------- final: mean + FC -> 2 outputs (dtype per flag) ----------
__global__ __launch_bounds__(512) void k_final(const float* __restrict__ partial,
                                               const float* __restrict__ fcWc,
                                               const float* __restrict__ fcbc,
                                               void* __restrict__ out,
                                               const int* __restrict__ flags) {
    __shared__ float sm[512];
    __shared__ float red[256];
    int t = threadIdx.x;
    int f = t & 127, c = t >> 7;
    float s = 0.f;
    for (int b = c; b < G2F; b += 4) s += partial[b * 128 + f];
    sm[t] = s;
    __syncthreads();
    if (t < 128) {
        float gm = (sm[t] + sm[t + 128] + sm[t + 256] + sm[t + 384]) * (1.0f / (float)N_NODES);
        red[t] = gm * fcWc[t];
        red[128 + t] = gm * fcWc[128 + t];
    }
    __syncthreads();
    for (int off = 64; off >= 1; off >>= 1) {
        if (t < off) {
            red[t] += red[t + off];
            red[128 + t] += red[128 + t + off];
        }
        __syncthreads();
    }
    if (t == 0) {
        float o0 = red[0] + fcbc[0];
        float o1 = red[128] + fcbc[1];
        if (flags[0]) {
            u16* ob = (u16*)out;
            ob[0] = f2bf(o0);
            ob[1] = f2bf(o1);
        } else {
            float* of = (float*)out;
            of[0] = o0;
            of[1] = o1;
        }
    }
}

// ---------- workspace layout (bytes) ----------
// csr int[E + NB*256 + pad] (self-loops + 64-entry overrun pad) = 13,200,384 B.
// agg (bf16, 12.8MB) aliases ebuf u32[E] (12.8MB): ebuf's last read (k_scatter2)
// precedes agg's first write (k_gatherM<1>) in stream order.
#define OFF_FLAGS   0u
#define OFF_DINV    512u         // float[N]
#define OFF_ROWPTR  400896u      // int[N+1]
#define OFF_BCNT    801280u      // u32[NB]
#define OFF_BBASE   802944u      // u32[NB+1]
#define OFF_BCUR    804608u      // u32[NB]
#define OFF_CSR     1201664u     // int[3300096]
#define OFF_H1      14402560u    // bf16[N*64]  (g1 = dinv*h1)
#define OFF_A1      27202560u    // bf16[N*64]  (a1s = dinv*relu(conv1))
#define OFF_AGG     40002560u    // bf16[N*64] (12.8MB) / ebuf u32[E] (12.8MB)
#define OFF_PART    52802560u    // float[G2F*128]
#define OFF_W1C     53122560u    // u16[256*64] (MFMA frag order)
#define OFF_W2C     53155328u    // u16[64*128] (MFMA frag order)
#define OFF_B1C     53171712u    // float[64]
#define OFF_B2C     53171968u    // float[128]
#define OFF_FCWC    53172480u    // float[256]
#define OFF_FCBC    53173504u    // float[2]

extern "C" void kernel_launch(void* const* d_in, const int* in_sizes, int n_in,
                              void* d_out, int out_size, void* d_ws, size_t ws_size,
                              hipStream_t stream) {
    (void)in_sizes; (void)n_in; (void)out_size; (void)ws_size;
    const void* x   = d_in[0];
    const int*  ei  = (const int*)d_in[1];
    const void* W1  = d_in[2];
    const void* b1  = d_in[3];
    const void* W2  = d_in[4];
    const void* b2  = d_in[5];
    const void* fcW = d_in[6];
    const void* fcb = d_in[7];

    char* ws = (char*)d_ws;
    int*   flags  = (int*)(ws + OFF_FLAGS);
    float* dinv   = (float*)(ws + OFF_DINV);
    int*   rowptr = (int*)(ws + OFF_ROWPTR);
    u32*   bcnt   = (u32*)(ws + OFF_BCNT);
    u32*   bbase  = (u32*)(ws + OFF_BBASE);
    u32*   bcur   = (u32*)(ws + OFF_BCUR);
    int*   csr    = (int*)(ws + OFF_CSR);
    u16*   g1     = (u16*)(ws + OFF_H1);
    u16*   a1s    = (u16*)(ws + OFF_A1);
    u16*   aggb   = (u16*)(ws + OFF_AGG);
    u32*   ebuf   = (u32*)(ws + OFF_AGG);
    float* partial= (float*)(ws + OFF_PART);
    u16*   W1m    = (u16*)(ws + OFF_W1C);
    u16*   W2m    = (u16*)(ws + OFF_W2C);
    float* b1c    = (float*)(ws + OFF_B1C);
    float* b2c    = (float*)(ws + OFF_B2C);
    float* fcWc   = (float*)(ws + OFF_FCWC);
    float* fcbc   = (float*)(ws + OFF_FCBC);

    k_detect<<<1, 256, 0, stream>>>(x, ei, b1, b2, fcW, fcb,
                                    flags, b1c, b2c, fcWc, fcbc);
    k_prep<<<96, 256, 0, stream>>>(W1, W2, flags, W1m, W2m, bcnt);
    k_hist1<<<NB, 256, 0, stream>>>(ei, flags, bcnt);
    k_bscan<<<1, 512, 0, stream>>>(bcnt, bbase, bcur, rowptr);
    k_scatter1<<<NB, 512, 0, stream>>>(ei, flags, bcur, ebuf);
    k_scatter2<<<NB, 256, 0, stream>>>(bbase, ebuf, rowptr, dinv, csr);
    k_gemm1<<<(N_NODES + 127) / 128, 256, 0, stream>>>(x, W1m, dinv, g1, flags);
    k_gatherM<0><<<G_GM, 256, 0, stream>>>(rowptr, csr, dinv, g1, b1c, a1s);
    k_gatherM<1><<<G_GM, 256, 0, stream>>>(rowptr, csr, dinv, a1s, b2c, aggb);
    k_fused2<<<G2F, 256, 0, stream>>>(aggb, W2m, b2c, partial);
    k_final<<<1, 512, 0, stream>>>(partial, fcWc, fcbc, (void*)d_out, flags);
}